// Round 10
// baseline (1210.919 us; speedup 1.0000x reference)
//
#include <hip/hip_runtime.h>
#include <math.h>

// KohnShamSolver: symmetric tridiagonal eigenproblem, N=4096.
//   d_i = 1/dx^2 + V_ext + V_H + V_xc + l(l+1)/(2 r^2);  e = -0.5/dx^2
// Out: [0,NX) eigvals f32; [NX..) eigvecs V[i*NX+k], sum_i V^2 vol = 1.
// R9 resubmit (broker timeout): vals gets 2 independent Sturm chains per lane
// (CPL=2 -> 32 probes, 33-section, VROUNDS 9->6). The second chain fills the
// dependent-FMA latency shadow that made R8 latency-bound (44.6 cy/step at
// 55% VALUBusy). disc/store unchanged from R6/R8 for clean attribution.

#define NX 4096
#define VROUNDS 6
#define SCL 480

__global__ __launch_bounds__(256) void build_diag_k(
    const int* __restrict__ lp, const float* __restrict__ Vext,
    const float* __restrict__ VH, const float* __restrict__ Vxc,
    const float* __restrict__ xc, const float* __restrict__ dxp,
    double* __restrict__ Dinv) {
  int i = blockIdx.x * 256 + threadIdx.x;
  double lf = (double)lp[0];
  double xr = (double)xc[i];
  double Vc = (xr > 1e-10) ? (lf * (lf + 1.0) / (2.0 * xr * xr)) : 0.0;
  double dx = (double)dxp[0];
  double d = (double)Vext[i] + (double)VH[i] + (double)Vxc[i] + Vc + 1.0 / (dx * dx);
  Dinv[i] = d * (-2.0 * dx * dx);   // d_i / e   (e = -0.5/dx^2)
}

// ---------------- eigenvalues: 16 lanes x 2 chains = 33-section ----------------
// q_{-1}=0, q_0=1, q_{i+1} = (D_i - xe) q_i - q_{i-1};  xe = x/e.
// Sign relation (e<0): cnt_p = NX - cnt_q.
#define PSTEP2(A) { \
  double pna = fma((A) - xea, p1a, -p2a); \
  double pnb = fma((A) - xeb, p1b, -p2b); \
  unsigned sa_ = ((unsigned)__double2hiint(pna)) >> 31; \
  unsigned sb_ = ((unsigned)__double2hiint(pnb)) >> 31; \
  cnta += (int)(sa_ ^ spa); cntb += (int)(sb_ ^ spb); \
  spa = sa_; spb = sb_; \
  p2a = p1a; p1a = pna; \
  p2b = p1b; p1b = pnb; }

__global__ __launch_bounds__(256) void eig_vals16_k(
    const double* __restrict__ Dinv, const float* __restrict__ dxp,
    double* __restrict__ lam, float* __restrict__ lamf) {
  __shared__ double sd[NX];
  for (int i = threadIdx.x; i < NX; i += 256) sd[i] = Dinv[i];
  __syncthreads();
  const double2* s2 = (const double2*)sd;
  int gt = blockIdx.x * 256 + threadIdx.x;
  int k = gt >> 4, t = gt & 15;
  double dxv = (double)dxp[0];
  double inv_e = -2.0 * dxv * dxv;
  double lo = -100.0, hi = 1200.0;  // Gershgorin-safe
  for (int it = 0; it < VROUNDS; ++it) {
    double h = (hi - lo) * (1.0 / 33.0);
    double xea = fma(h, (double)(t + 1), lo) * inv_e;   // probe m = t+1
    double xeb = fma(h, (double)(t + 17), lo) * inv_e;  // probe m = t+17
    double p1a = 1.0, p2a = 0.0, p1b = 1.0, p2b = 0.0;
    unsigned spa = 0, spb = 0;
    int cnta = 0, cntb = 0;
    double2 a0 = s2[0], a1 = s2[1], a2 = s2[2], a3 = s2[3];
    for (int b = 0; b < 512; ++b) {
      int n4 = ((b + 1) << 2) & 2047;   // wraps harmlessly on last block
      double2 n0 = s2[n4], n1 = s2[n4 + 1], n2 = s2[n4 + 2], n3 = s2[n4 + 3];
      PSTEP2(a0.x) PSTEP2(a0.y) PSTEP2(a1.x) PSTEP2(a1.y)
      PSTEP2(a2.x) PSTEP2(a2.y) PSTEP2(a3.x) PSTEP2(a3.y)
      double apa = fabs(p1a);           // positive rescale preserves signs
      if (apa > 0x1p+600) { p1a *= 0x1p-600; p2a *= 0x1p-600; }
      else if (apa < 0x1p-600 && apa > 0.0) { p1a *= 0x1p+600; p2a *= 0x1p+600; }
      double apb = fabs(p1b);
      if (apb > 0x1p+600) { p1b *= 0x1p-600; p2b *= 0x1p-600; }
      else if (apb < 0x1p-600 && apb > 0.0) { p1b *= 0x1p+600; p2b *= 0x1p+600; }
      a0 = n0; a1 = n1; a2 = n2; a3 = n3;
    }
    int f = (((NX - cnta) <= k) ? 1 : 0) + (((NX - cntb) <= k) ? 1 : 0);
    f += __shfl_xor(f, 1, 16);
    f += __shfl_xor(f, 2, 16);
    f += __shfl_xor(f, 4, 16);
    f += __shfl_xor(f, 8, 16);
    lo = fma(h, (double)f, lo);   // bracket = [lo + f h, lo + (f+1) h]
    hi = lo + h;
  }
  if (t == 0) {
    double v = 0.5 * (lo + hi);
    lam[k] = v;
    lamf[k] = (float)v;
  }
}

// ---------------- vecs A: discovery (2 lanes/col) ----------------
// chain: y_{next} = (xe - D) y - y_prev.  Analytic weight sqrt tt = row+1.
#define S1STEP(A) { \
  double cc = xe - (A); \
  double yn = fma(cc, y1, -y0); \
  y0 = y1; y1 = yn; \
  double yt = yn * tt; \
  S = fma(yt, yt, S); \
  tt += dtt; \
  double ay = fabs(yn); \
  if (ay > amax) { amax = ay; r = eN; } \
  eN += estep; }

#define RESC1() { double ay = fabs(y1); \
  if (ay > 0x1p+480) { y1 *= 0x1p-480; y0 *= 0x1p-480; S *= 0x1p-960; amax *= 0x1p-480; j++; } \
  else if (ay < 0x1p-480 && ay > 0.0) { y1 *= 0x1p+480; y0 *= 0x1p+480; S *= 0x1p+960; amax *= 0x1p+480; j--; } }

__global__ __launch_bounds__(64) void eig_vecs_disc_k(
    const double* __restrict__ Dinv, const double* __restrict__ lam,
    const float* __restrict__ dxp,
    double* __restrict__ fmA, int* __restrict__ feA, int* __restrict__ rrA,
    double* __restrict__ cky1, double* __restrict__ cky0, int* __restrict__ ckj) {
  __shared__ double sdf[NX], sdr[NX];
  for (int i = threadIdx.x; i < NX; i += 64) { sdf[i] = Dinv[i]; sdr[i] = Dinv[NX - 1 - i]; }
  __syncthreads();
  int lane = threadIdx.x, dir = lane & 1;
  int col = blockIdx.x * 32 + (lane >> 1);
  double x = lam[col];
  double dxv = (double)dxp[0];
  double inv_e = -2.0 * dxv * dxv;
  double xe = x * inv_e;
  const double* msd = dir ? sdr : sdf;
  const double2* s2 = (const double2*)msd;

  double y1 = 1.0, y0 = 0.0;
  double S = dir ? 16777216.0 : 1.0;     // (4096)^2 : 1^2
  double tt = dir ? 4095.0 : 2.0;        // weight sqrt of first produced row
  double dtt = dir ? -1.0 : 1.0;
  int j = 0;
  double amax = 1.0;
  int r = dir ? (NX - 1) : 0;
  int eN = dir ? (NX - 2) : 1;
  int estep = dir ? -1 : 1;
  double k1y1 = 1.0, k1y0 = 0.0, k1S = S; int k1j = 0;
  double k2y1 = 1.0, k2y0 = 0.0, k2S = S; int k2j = 0;
  double k3y1 = 1.0, k3y0 = 0.0, k3S = S; int k3j = 0;
  {
    double2 a0 = s2[0], a1 = s2[1], a2 = s2[2], a3 = s2[3];
    for (int b = 0; b < 511; ++b) {
      int n4 = (b + 1) << 2;
      double2 n0 = s2[n4], n1 = s2[n4 + 1], n2 = s2[n4 + 2], n3 = s2[n4 + 3];
      S1STEP(a0.x) S1STEP(a0.y) S1STEP(a1.x) S1STEP(a1.y)
      S1STEP(a2.x) S1STEP(a2.y) S1STEP(a3.x) S1STEP(a3.y)
      RESC1();
      if (b == 127)      { k1y1 = y1; k1y0 = y0; k1S = S; k1j = j; }
      else if (b == 255) { k2y1 = y1; k2y0 = y0; k2S = S; k2j = j; }
      else if (b == 383) { k3y1 = y1; k3y0 = y0; k3S = S; k3j = j; }
      a0 = n0; a1 = n1; a2 = n2; a3 = n3;
    }
    S1STEP(a0.x) S1STEP(a0.y) S1STEP(a1.x) S1STEP(a1.y)
    S1STEP(a2.x) S1STEP(a2.y) S1STEP(a3.x)        // steps 4088..4094
  }
  { int rr_ = __shfl_xor(r, 1, 64); if (!dir) r = rr_; }

  // mini-replay from checkpoint: chain value at r + partial weighted sum
  int tcount = dir ? (NX - 1 - r) : r;
  int c = tcount >> 10, Tstart = c << 10, cntr = tcount - Tstart;
  double ry1 = (c == 0) ? 1.0 : (c == 1) ? k1y1 : (c == 2) ? k2y1 : k3y1;
  double ry0 = (c == 0) ? 0.0 : (c == 1) ? k1y0 : (c == 2) ? k2y0 : k3y0;
  double rS  = (c == 0) ? (dir ? 16777216.0 : 1.0) : (c == 1) ? k1S : (c == 2) ? k2S : k3S;
  int rj = (c == 0) ? 0 : (c == 1) ? k1j : (c == 2) ? k2j : k3j;
  double rtt = dir ? (double)(NX - 1 - Tstart) : (double)(Tstart + 2);
  #pragma unroll 4
  for (int s = 0; s < 1024; ++s) {
    double sdv = msd[Tstart + s];
    if (s < cntr) {
      double cc = xe - sdv;
      double yn = fma(cc, ry1, -ry0);
      ry0 = ry1; ry1 = yn;
      double yt = yn * rtt;
      rS = fma(yt, yt, rS);
      rtt += dtt;
      if ((s & 7) == 7) {   // identical cadence/thresholds as S1 (bit-deterministic)
        double ay = fabs(ry1);
        if (ay > 0x1p+480) { ry1 *= 0x1p-480; ry0 *= 0x1p-480; rS *= 0x1p-960; rj++; }
        else if (ay < 0x1p-480 && ay > 0.0) { ry1 *= 0x1p+480; ry0 *= 0x1p+480; rS *= 0x1p+960; rj--; }
      }
    }
  }
  double yr2 = ry1 * ry1;
  double volr = (double)((r + 1) * (r + 1));
  double term = dir ? (rS / yr2)
                    : ((r > 0) ? (rS - yr2 * volr) / yr2 : 0.0);
  double other = __shfl_xor(term, 1, 64);
  double K = 12.566370614359172 * dxv * dxv * dxv;   // 4*pi*dx^3
  double snn = 1.0 / sqrt((term + other) * K);
  double fm = snn / ry1;
  int fe = -SCL * rj;

  fmA[dir * NX + col] = fm;
  feA[dir * NX + col] = fe;
  if (!dir) rrA[col] = r;
  int c0 = (dir * 3) * NX + col;
  cky1[c0] = k1y1;          cky0[c0] = k1y0;          ckj[c0] = k1j;
  cky1[c0 + NX] = k2y1;     cky0[c0 + NX] = k2y0;     ckj[c0 + NX] = k2j;
  cky1[c0 + 2 * NX] = k3y1; cky0[c0 + 2 * NX] = k3y0; ckj[c0 + 2 * NX] = k3j;
}

// ---------------- vecs B: parallel store (8 lanes/col = 2 dirs x 4 chunks) ----------------
#define BSTEP(A) { \
  double cc = xe - (A); \
  double yn = fma(cc, y1, -y0); \
  y0 = y1; y1 = yn; \
  if (s < sb) V[off] = (float)(yn * fms); \
  ++s; off += doff; }

#define BRESC() { double ay = fabs(y1); \
  if (ay > 0x1p+480) { y1 *= 0x1p-480; y0 *= 0x1p-480; j++; fms = ldexp(fm, fe + SCL * j); } \
  else if (ay < 0x1p-480 && ay > 0.0) { y1 *= 0x1p+480; y0 *= 0x1p+480; j--; fms = ldexp(fm, fe + SCL * j); } }

__global__ __launch_bounds__(256) void eig_vecs_store_k(
    const double* __restrict__ Dinv, const double* __restrict__ lam,
    const float* __restrict__ dxp,
    const double* __restrict__ fmA, const int* __restrict__ feA,
    const int* __restrict__ rrA,
    const double* __restrict__ cky1, const double* __restrict__ cky0,
    const int* __restrict__ ckj,
    float* __restrict__ V) {
  int sub = blockIdx.x >> 4;          // 0..7
  int dir = sub & 1, chunk = sub >> 1;
  int col = (blockIdx.x & 15) * 256 + threadIdx.x;
  __shared__ double sD[NX];
  for (int i = threadIdx.x; i < NX; i += 256) sD[i] = dir ? Dinv[NX - 1 - i] : Dinv[i];
  __syncthreads();
  double x = lam[col];
  double dxv = (double)dxp[0];
  double inv_e = -2.0 * dxv * dxv;
  double xe = x * inv_e;
  int r = rrA[col];
  double fm = fmA[dir * NX + col];
  int fe = feA[dir * NX + col];
  double y1, y0; int j;
  if (chunk == 0) { y1 = 1.0; y0 = 0.0; j = 0; }
  else {
    int ci = (dir * 3 + (chunk - 1)) * NX + col;
    y1 = cky1[ci]; y0 = cky0[ci]; j = ckj[ci];
  }
  double fms = ldexp(fm, fe + SCL * j);
  int g0 = chunk << 10;
  int L = (chunk < 3) ? 1024 : 1023;
  if (chunk == 0) {         // boundary rows (chain value 1, epoch 0)
    if (dir) V[(size_t)(NX - 1) * NX + col] = (float)fms;
    else if (r > 0) V[col] = (float)fms;
  }
  int sb = dir ? (NX - 1 - r - g0) : (r - 1 - g0);
  if (sb < 0) sb = 0;
  if (sb > L) sb = L;
  long off = dir ? ((long)(NX - 2 - g0) * NX + col) : ((long)(g0 + 1) * NX + col);
  long doff = dir ? -(long)NX : (long)NX;
  const double2* t2 = (const double2*)(sD + g0);
  double2 a0 = t2[0], a1 = t2[1], a2 = t2[2], a3 = t2[3];
  int s = 0;
  for (int b = 0; b < 128; ++b) {
    int n4 = ((b + 1) << 2) & 511;    // wraps harmlessly on last block
    double2 n0 = t2[n4], n1 = t2[n4 + 1], n2 = t2[n4 + 2], n3 = t2[n4 + 3];
    BSTEP(a0.x) BSTEP(a0.y) BSTEP(a1.x) BSTEP(a1.y)
    BSTEP(a2.x) BSTEP(a2.y) BSTEP(a3.x) BSTEP(a3.y)
    BRESC();
    a0 = n0; a1 = n1; a2 = n2; a3 = n3;
  }
}

extern "C" void kernel_launch(void* const* d_in, const int* in_sizes, int n_in,
                              void* d_out, int out_size, void* d_ws, size_t ws_size,
                              hipStream_t stream) {
  const int*   l    = (const int*)d_in[0];
  const float* Vext = (const float*)d_in[1];
  const float* VH   = (const float*)d_in[2];
  const float* Vxc  = (const float*)d_in[3];
  const float* xc   = (const float*)d_in[4];
  const float* dx   = (const float*)d_in[6];
  float* out = (float*)d_out;

  double* Dinv = (double*)d_ws;          // NX
  double* lam  = Dinv + NX;              // NX
  double* fmA  = lam + NX;               // 2*NX
  double* cky1 = fmA + 2 * NX;           // 6*NX
  double* cky0 = cky1 + 6 * NX;          // 6*NX
  int*    feA  = (int*)(cky0 + 6 * NX);  // 2*NX
  int*    rrA  = feA + 2 * NX;           // NX
  int*    ckj  = rrA + NX;               // 6*NX

  build_diag_k<<<NX / 256, 256, 0, stream>>>(l, Vext, VH, Vxc, xc, dx, Dinv);
  eig_vals16_k<<<(NX * 16) / 256, 256, 0, stream>>>(Dinv, dx, lam, out);
  eig_vecs_disc_k<<<NX / 32, 64, 0, stream>>>(Dinv, lam, dx, fmA, feA, rrA, cky1, cky0, ckj);
  eig_vecs_store_k<<<128, 256, 0, stream>>>(Dinv, lam, dx, fmA, feA, rrA, cky1, cky0, ckj, out + NX);
}

// Round 12
// 1013.268 us; speedup vs baseline: 1.1951x; 1.1951x over previous
//
#include <hip/hip_runtime.h>
#include <math.h>

// KohnShamSolver: symmetric tridiagonal eigenproblem, N=4096.
//   d_i = 1/dx^2 + V_ext + V_H + V_xc + l(l+1)/(2 r^2);  e = -0.5/dx^2
// Out: [0,NX) eigvals f32; [NX..) eigvecs V[i*NX+k], sum_i V^2 vol = 1.
// R11 resubmit (broker timeout): vals = 32 LANES per eigenvalue (33-section,
// VROUNDS=6), one Sturm chain per lane -> 512 blocks = 2 waves/SIMD. R10
// showed the ~20cy/step stall is not fillable by in-stream ILP (CPL=2
// regressed); this fills it with a co-resident wave (TLP). disc/store
// unchanged.

#define NX 4096
#define VROUNDS 6
#define SCL 480

__global__ __launch_bounds__(256) void build_diag_k(
    const int* __restrict__ lp, const float* __restrict__ Vext,
    const float* __restrict__ VH, const float* __restrict__ Vxc,
    const float* __restrict__ xc, const float* __restrict__ dxp,
    double* __restrict__ Dinv) {
  int i = blockIdx.x * 256 + threadIdx.x;
  double lf = (double)lp[0];
  double xr = (double)xc[i];
  double Vc = (xr > 1e-10) ? (lf * (lf + 1.0) / (2.0 * xr * xr)) : 0.0;
  double dx = (double)dxp[0];
  double d = (double)Vext[i] + (double)VH[i] + (double)Vxc[i] + Vc + 1.0 / (dx * dx);
  Dinv[i] = d * (-2.0 * dx * dx);   // d_i / e   (e = -0.5/dx^2)
}

// ---------------- eigenvalues: 32 lanes x 1 chain = 33-section ----------------
// q_{-1}=0, q_0=1, q_{i+1} = (D_i - xe) q_i - q_{i-1};  xe = x/e.
// Sign relation (e<0): cnt_p = NX - cnt_q.
#define PSTEP(A) { double pn = fma((A) - xe, p1, -p2); \
  unsigned sn_ = ((unsigned)__double2hiint(pn)) >> 31; \
  cnt += (int)(sn_ ^ sp); sp = sn_; p2 = p1; p1 = pn; }

__global__ __launch_bounds__(256) void eig_vals32_k(
    const double* __restrict__ Dinv, const float* __restrict__ dxp,
    double* __restrict__ lam, float* __restrict__ lamf) {
  __shared__ double sd[NX];
  for (int i = threadIdx.x; i < NX; i += 256) sd[i] = Dinv[i];
  __syncthreads();
  const double2* s2 = (const double2*)sd;
  int gt = blockIdx.x * 256 + threadIdx.x;
  int k = gt >> 5, t = gt & 31;
  double dxv = (double)dxp[0];
  double inv_e = -2.0 * dxv * dxv;
  double lo = -100.0, hi = 1200.0;  // Gershgorin-safe
  for (int it = 0; it < VROUNDS; ++it) {
    double h = (hi - lo) * (1.0 / 33.0);
    double xe = fma(h, (double)(t + 1), lo) * inv_e;   // probe m = t+1, m in 1..32
    double p1 = 1.0, p2 = 0.0;
    unsigned sp = 0; int cnt = 0;
    double2 a0 = s2[0], a1 = s2[1], a2 = s2[2], a3 = s2[3];
    for (int b = 0; b < 512; ++b) {
      int n4 = ((b + 1) << 2) & 2047;   // wraps harmlessly on last block
      double2 n0 = s2[n4], n1 = s2[n4 + 1], n2 = s2[n4 + 2], n3 = s2[n4 + 3];
      PSTEP(a0.x) PSTEP(a0.y) PSTEP(a1.x) PSTEP(a1.y)
      PSTEP(a2.x) PSTEP(a2.y) PSTEP(a3.x) PSTEP(a3.y)
      double ap = fabs(p1);             // positive rescale preserves signs
      if (ap > 0x1p+600) { p1 *= 0x1p-600; p2 *= 0x1p-600; }
      else if (ap < 0x1p-600 && ap > 0.0) { p1 *= 0x1p+600; p2 *= 0x1p+600; }
      a0 = n0; a1 = n1; a2 = n2; a3 = n3;
    }
    int f = ((NX - cnt) <= k) ? 1 : 0;  // monotone flags over 32 probes
    f += __shfl_xor(f, 1, 32);
    f += __shfl_xor(f, 2, 32);
    f += __shfl_xor(f, 4, 32);
    f += __shfl_xor(f, 8, 32);
    f += __shfl_xor(f, 16, 32);
    lo = fma(h, (double)f, lo);   // bracket = [lo + f h, lo + (f+1) h]
    hi = lo + h;
  }
  if (t == 0) {
    double v = 0.5 * (lo + hi);
    lam[k] = v;
    lamf[k] = (float)v;
  }
}

// ---------------- vecs A: discovery (2 lanes/col) ----------------
// chain: y_{next} = (xe - D) y - y_prev.  Analytic weight sqrt tt = row+1.
#define S1STEP(A) { \
  double cc = xe - (A); \
  double yn = fma(cc, y1, -y0); \
  y0 = y1; y1 = yn; \
  double yt = yn * tt; \
  S = fma(yt, yt, S); \
  tt += dtt; \
  double ay = fabs(yn); \
  if (ay > amax) { amax = ay; r = eN; } \
  eN += estep; }

#define RESC1() { double ay = fabs(y1); \
  if (ay > 0x1p+480) { y1 *= 0x1p-480; y0 *= 0x1p-480; S *= 0x1p-960; amax *= 0x1p-480; j++; } \
  else if (ay < 0x1p-480 && ay > 0.0) { y1 *= 0x1p+480; y0 *= 0x1p+480; S *= 0x1p+960; amax *= 0x1p+480; j--; } }

__global__ __launch_bounds__(64) void eig_vecs_disc_k(
    const double* __restrict__ Dinv, const double* __restrict__ lam,
    const float* __restrict__ dxp,
    double* __restrict__ fmA, int* __restrict__ feA, int* __restrict__ rrA,
    double* __restrict__ cky1, double* __restrict__ cky0, int* __restrict__ ckj) {
  __shared__ double sdf[NX], sdr[NX];
  for (int i = threadIdx.x; i < NX; i += 64) { sdf[i] = Dinv[i]; sdr[i] = Dinv[NX - 1 - i]; }
  __syncthreads();
  int lane = threadIdx.x, dir = lane & 1;
  int col = blockIdx.x * 32 + (lane >> 1);
  double x = lam[col];
  double dxv = (double)dxp[0];
  double inv_e = -2.0 * dxv * dxv;
  double xe = x * inv_e;
  const double* msd = dir ? sdr : sdf;
  const double2* s2 = (const double2*)msd;

  double y1 = 1.0, y0 = 0.0;
  double S = dir ? 16777216.0 : 1.0;     // (4096)^2 : 1^2
  double tt = dir ? 4095.0 : 2.0;        // weight sqrt of first produced row
  double dtt = dir ? -1.0 : 1.0;
  int j = 0;
  double amax = 1.0;
  int r = dir ? (NX - 1) : 0;
  int eN = dir ? (NX - 2) : 1;
  int estep = dir ? -1 : 1;
  double k1y1 = 1.0, k1y0 = 0.0, k1S = S; int k1j = 0;
  double k2y1 = 1.0, k2y0 = 0.0, k2S = S; int k2j = 0;
  double k3y1 = 1.0, k3y0 = 0.0, k3S = S; int k3j = 0;
  {
    double2 a0 = s2[0], a1 = s2[1], a2 = s2[2], a3 = s2[3];
    for (int b = 0; b < 511; ++b) {
      int n4 = (b + 1) << 2;
      double2 n0 = s2[n4], n1 = s2[n4 + 1], n2 = s2[n4 + 2], n3 = s2[n4 + 3];
      S1STEP(a0.x) S1STEP(a0.y) S1STEP(a1.x) S1STEP(a1.y)
      S1STEP(a2.x) S1STEP(a2.y) S1STEP(a3.x) S1STEP(a3.y)
      RESC1();
      if (b == 127)      { k1y1 = y1; k1y0 = y0; k1S = S; k1j = j; }
      else if (b == 255) { k2y1 = y1; k2y0 = y0; k2S = S; k2j = j; }
      else if (b == 383) { k3y1 = y1; k3y0 = y0; k3S = S; k3j = j; }
      a0 = n0; a1 = n1; a2 = n2; a3 = n3;
    }
    S1STEP(a0.x) S1STEP(a0.y) S1STEP(a1.x) S1STEP(a1.y)
    S1STEP(a2.x) S1STEP(a2.y) S1STEP(a3.x)        // steps 4088..4094
  }
  { int rr_ = __shfl_xor(r, 1, 64); if (!dir) r = rr_; }

  // mini-replay from checkpoint: chain value at r + partial weighted sum
  int tcount = dir ? (NX - 1 - r) : r;
  int c = tcount >> 10, Tstart = c << 10, cntr = tcount - Tstart;
  double ry1 = (c == 0) ? 1.0 : (c == 1) ? k1y1 : (c == 2) ? k2y1 : k3y1;
  double ry0 = (c == 0) ? 0.0 : (c == 1) ? k1y0 : (c == 2) ? k2y0 : k3y0;
  double rS  = (c == 0) ? (dir ? 16777216.0 : 1.0) : (c == 1) ? k1S : (c == 2) ? k2S : k3S;
  int rj = (c == 0) ? 0 : (c == 1) ? k1j : (c == 2) ? k2j : k3j;
  double rtt = dir ? (double)(NX - 1 - Tstart) : (double)(Tstart + 2);
  #pragma unroll 4
  for (int s = 0; s < 1024; ++s) {
    double sdv = msd[Tstart + s];
    if (s < cntr) {
      double cc = xe - sdv;
      double yn = fma(cc, ry1, -ry0);
      ry0 = ry1; ry1 = yn;
      double yt = yn * rtt;
      rS = fma(yt, yt, rS);
      rtt += dtt;
      if ((s & 7) == 7) {   // identical cadence/thresholds as S1 (bit-deterministic)
        double ay = fabs(ry1);
        if (ay > 0x1p+480) { ry1 *= 0x1p-480; ry0 *= 0x1p-480; rS *= 0x1p-960; rj++; }
        else if (ay < 0x1p-480 && ay > 0.0) { ry1 *= 0x1p+480; ry0 *= 0x1p+480; rS *= 0x1p+960; rj--; }
      }
    }
  }
  double yr2 = ry1 * ry1;
  double volr = (double)((r + 1) * (r + 1));
  double term = dir ? (rS / yr2)
                    : ((r > 0) ? (rS - yr2 * volr) / yr2 : 0.0);
  double other = __shfl_xor(term, 1, 64);
  double K = 12.566370614359172 * dxv * dxv * dxv;   // 4*pi*dx^3
  double snn = 1.0 / sqrt((term + other) * K);
  double fm = snn / ry1;
  int fe = -SCL * rj;

  fmA[dir * NX + col] = fm;
  feA[dir * NX + col] = fe;
  if (!dir) rrA[col] = r;
  int c0 = (dir * 3) * NX + col;
  cky1[c0] = k1y1;          cky0[c0] = k1y0;          ckj[c0] = k1j;
  cky1[c0 + NX] = k2y1;     cky0[c0 + NX] = k2y0;     ckj[c0 + NX] = k2j;
  cky1[c0 + 2 * NX] = k3y1; cky0[c0 + 2 * NX] = k3y0; ckj[c0 + 2 * NX] = k3j;
}

// ---------------- vecs B: parallel store (8 lanes/col = 2 dirs x 4 chunks) ----------------
#define BSTEP(A) { \
  double cc = xe - (A); \
  double yn = fma(cc, y1, -y0); \
  y0 = y1; y1 = yn; \
  if (s < sb) V[off] = (float)(yn * fms); \
  ++s; off += doff; }

#define BRESC() { double ay = fabs(y1); \
  if (ay > 0x1p+480) { y1 *= 0x1p-480; y0 *= 0x1p-480; j++; fms = ldexp(fm, fe + SCL * j); } \
  else if (ay < 0x1p-480 && ay > 0.0) { y1 *= 0x1p+480; y0 *= 0x1p+480; j--; fms = ldexp(fm, fe + SCL * j); } }

__global__ __launch_bounds__(256) void eig_vecs_store_k(
    const double* __restrict__ Dinv, const double* __restrict__ lam,
    const float* __restrict__ dxp,
    const double* __restrict__ fmA, const int* __restrict__ feA,
    const int* __restrict__ rrA,
    const double* __restrict__ cky1, const double* __restrict__ cky0,
    const int* __restrict__ ckj,
    float* __restrict__ V) {
  int sub = blockIdx.x >> 4;          // 0..7
  int dir = sub & 1, chunk = sub >> 1;
  int col = (blockIdx.x & 15) * 256 + threadIdx.x;
  __shared__ double sD[NX];
  for (int i = threadIdx.x; i < NX; i += 256) sD[i] = dir ? Dinv[NX - 1 - i] : Dinv[i];
  __syncthreads();
  double x = lam[col];
  double dxv = (double)dxp[0];
  double inv_e = -2.0 * dxv * dxv;
  double xe = x * inv_e;
  int r = rrA[col];
  double fm = fmA[dir * NX + col];
  int fe = feA[dir * NX + col];
  double y1, y0; int j;
  if (chunk == 0) { y1 = 1.0; y0 = 0.0; j = 0; }
  else {
    int ci = (dir * 3 + (chunk - 1)) * NX + col;
    y1 = cky1[ci]; y0 = cky0[ci]; j = ckj[ci];
  }
  double fms = ldexp(fm, fe + SCL * j);
  int g0 = chunk << 10;
  int L = (chunk < 3) ? 1024 : 1023;
  if (chunk == 0) {         // boundary rows (chain value 1, epoch 0)
    if (dir) V[(size_t)(NX - 1) * NX + col] = (float)fms;
    else if (r > 0) V[col] = (float)fms;
  }
  int sb = dir ? (NX - 1 - r - g0) : (r - 1 - g0);
  if (sb < 0) sb = 0;
  if (sb > L) sb = L;
  long off = dir ? ((long)(NX - 2 - g0) * NX + col) : ((long)(g0 + 1) * NX + col);
  long doff = dir ? -(long)NX : (long)NX;
  const double2* t2 = (const double2*)(sD + g0);
  double2 a0 = t2[0], a1 = t2[1], a2 = t2[2], a3 = t2[3];
  int s = 0;
  for (int b = 0; b < 128; ++b) {
    int n4 = ((b + 1) << 2) & 511;    // wraps harmlessly on last block
    double2 n0 = t2[n4], n1 = t2[n4 + 1], n2 = t2[n4 + 2], n3 = t2[n4 + 3];
    BSTEP(a0.x) BSTEP(a0.y) BSTEP(a1.x) BSTEP(a1.y)
    BSTEP(a2.x) BSTEP(a2.y) BSTEP(a3.x) BSTEP(a3.y)
    BRESC();
    a0 = n0; a1 = n1; a2 = n2; a3 = n3;
  }
}

extern "C" void kernel_launch(void* const* d_in, const int* in_sizes, int n_in,
                              void* d_out, int out_size, void* d_ws, size_t ws_size,
                              hipStream_t stream) {
  const int*   l    = (const int*)d_in[0];
  const float* Vext = (const float*)d_in[1];
  const float* VH   = (const float*)d_in[2];
  const float* Vxc  = (const float*)d_in[3];
  const float* xc   = (const float*)d_in[4];
  const float* dx   = (const float*)d_in[6];
  float* out = (float*)d_out;

  double* Dinv = (double*)d_ws;          // NX
  double* lam  = Dinv + NX;              // NX
  double* fmA  = lam + NX;               // 2*NX
  double* cky1 = fmA + 2 * NX;           // 6*NX
  double* cky0 = cky1 + 6 * NX;          // 6*NX
  int*    feA  = (int*)(cky0 + 6 * NX);  // 2*NX
  int*    rrA  = feA + 2 * NX;           // NX
  int*    ckj  = rrA + NX;               // 6*NX

  build_diag_k<<<NX / 256, 256, 0, stream>>>(l, Vext, VH, Vxc, xc, dx, Dinv);
  eig_vals32_k<<<(NX * 32) / 256, 256, 0, stream>>>(Dinv, dx, lam, out);
  eig_vecs_disc_k<<<NX / 32, 64, 0, stream>>>(Dinv, lam, dx, fmA, feA, rrA, cky1, cky0, ckj);
  eig_vecs_store_k<<<128, 256, 0, stream>>>(Dinv, lam, dx, fmA, feA, rrA, cky1, cky0, ckj, out + NX);
}